// Round 8
// baseline (443.745 us; speedup 1.0000x reference)
//
#include <hip/hip_runtime.h>
#include <hip/hip_bf16.h>

// GRNN tree transform v6: 5 launches, no in-kernel grid barrier.
//  1. k_leaf: leaf emb + u_small(levels 0..9) + w_h cast + ids BFS precompute
//  2. k_inner j=11 (emb12->emb11)   3. k_inner j=10 (emb11->emb10)
//  4. k_tailA: levels 9..4 as 1024 level-4-rooted subtrees (1 block each,
//     4 blocks/CU full co-residency), ids from precomputed flat lists.
//  5. k_tailB: levels 3..0 as 64 level-0-rooted subtrees -> d_out.
// Children are per-level permutations -> disjoint perfect subtrees; BFS order
// makes child rows of node i = prev-output rows 2i/2i+1.

#define NF 7
#define NH 128
#define NLEAF 262144
#define XSTR 136      // k_inner xs stride (bf16)
#define XSTR3 392     // tail xs stride: 384 + 8 pad (row 784 B, 16B-aligned)

typedef __bf16 bf16;
typedef __bf16 bf16x8 __attribute__((ext_vector_type(8)));
typedef float floatx16 __attribute__((ext_vector_type(16)));

__device__ __forceinline__ float ftanh(float x){
    float e = __expf(2.0f * x);
    return 1.0f - __fdividef(2.0f, e + 1.0f);
}

// ---------- launch 1: leaf emb + u_small + wcast + ids BFS ----------
// grid 2565: [0,2048) leaf tiles; [2048,2560) u tiles; [2560,2564) ids_A; 2564 ids_B.
__global__ __launch_bounds__(256) void k_leaf(
    const float* __restrict__ contents, const int2* __restrict__ children,
    const float* __restrict__ w_u, const float* __restrict__ b_u,
    const float* __restrict__ w_h,
    unsigned int* __restrict__ embA_u32, unsigned int* __restrict__ usm_u32,
    bf16* __restrict__ wb, int* __restrict__ ids_A, int* __restrict__ ids_B)
{
    const int t = threadIdx.x;
    const int b = blockIdx.x;

    if (b >= 2560){
        if (b < 2564){
            // ids_A: per-thread BFS, root at level 4, record levels 4..9 + level-10 children
            int root = (b - 2560) * 256 + t;           // 0..1023
            int* base = ids_A + root * 128;
            const int2* ch4 = children + 960;          // 64*(2^4-1)
            const int2* ch5 = children + 1984;
            const int2* ch6 = children + 4032;
            const int2* ch7 = children + 8128;
            const int2* ch8 = children + 16320;
            const int2* ch9 = children + 32704;
            int l5[2], l6[4], l7[8], l8[16], l9[32];
            { int2 c = ch4[root]; l5[0] = c.x; l5[1] = c.y; }
            #pragma unroll
            for (int k = 0; k < 2; ++k){ int2 c = ch5[l5[k]]; l6[2*k] = c.x; l6[2*k+1] = c.y; }
            #pragma unroll
            for (int k = 0; k < 4; ++k){ int2 c = ch6[l6[k]]; l7[2*k] = c.x; l7[2*k+1] = c.y; }
            #pragma unroll
            for (int k = 0; k < 8; ++k){ int2 c = ch7[l7[k]]; l8[2*k] = c.x; l8[2*k+1] = c.y; }
            #pragma unroll
            for (int k = 0; k < 16; ++k){ int2 c = ch8[l8[k]]; l9[2*k] = c.x; l9[2*k+1] = c.y; }
            base[0] = root;
            base[1] = l5[0]; base[2] = l5[1];
            #pragma unroll
            for (int k = 0; k < 4; ++k)  base[3 + k]  = l6[k];
            #pragma unroll
            for (int k = 0; k < 8; ++k)  base[7 + k]  = l7[k];
            #pragma unroll
            for (int k = 0; k < 16; ++k) base[15 + k] = l8[k];
            #pragma unroll
            for (int k = 0; k < 32; ++k) base[31 + k] = l9[k];
            #pragma unroll
            for (int k = 0; k < 32; ++k){
                int2 c = ch9[l9[k]];
                base[63 + 2*k] = c.x; base[64 + 2*k] = c.y;
            }
        } else if (t < 64){
            // ids_B: root at level 0, levels 0..3 + level-4 children
            int root = t;
            int* base = ids_B + root * 32;
            const int2* ch0 = children;
            const int2* ch1 = children + 64;
            const int2* ch2 = children + 192;
            const int2* ch3 = children + 448;
            int l1[2], l2[4], l3[8];
            { int2 c = ch0[root]; l1[0] = c.x; l1[1] = c.y; }
            #pragma unroll
            for (int k = 0; k < 2; ++k){ int2 c = ch1[l1[k]]; l2[2*k] = c.x; l2[2*k+1] = c.y; }
            #pragma unroll
            for (int k = 0; k < 4; ++k){ int2 c = ch2[l2[k]]; l3[2*k] = c.x; l3[2*k+1] = c.y; }
            base[0] = root;
            base[1] = l1[0]; base[2] = l1[1];
            #pragma unroll
            for (int k = 0; k < 4; ++k) base[3 + k] = l2[k];
            #pragma unroll
            for (int k = 0; k < 8; ++k) base[7 + k] = l3[k];
            #pragma unroll
            for (int k = 0; k < 8; ++k){
                int2 c = ch3[l3[k]];
                base[15 + 2*k] = c.x; base[16 + 2*k] = c.y;
            }
        }
        return;
    }

    __shared__ float csL[128 * 8];
    if (b < 192) wb[b * 256 + t] = (bf16)w_h[b * 256 + t];

    const int leaf = (b < 2048);
    const size_t srow = leaf ? (262080 + (size_t)b * 128) : ((size_t)(b - 2048) * 128);
    unsigned int* dst = leaf ? embA_u32 : usm_u32;
    const size_t drow = leaf ? ((size_t)b * 128) : ((size_t)(b - 2048) * 128);

    if (t < 224){
        float4 v = ((const float4*)(contents + srow * NF))[t];
        int e = t * 4;
        float vv[4] = {v.x, v.y, v.z, v.w};
        #pragma unroll
        for (int r = 0; r < 4; ++r){ int ee = e + r; csL[(ee/7)*8 + (ee%7)] = vv[r]; }
    }
    const int cp = t & 63;
    const int quarter = t >> 6;
    float wu0[NF], wu1[NF];
    const float* w0 = w_u + (size_t)(2 * cp) * NF;
    #pragma unroll
    for (int f = 0; f < NF; ++f){ wu0[f] = w0[f]; wu1[f] = w0[NF + f]; }
    const float bu0 = b_u[2 * cp], bu1 = b_u[2 * cp + 1];
    __syncthreads();
    #pragma unroll 4
    for (int i = 0; i < 32; ++i){
        int node = quarter * 32 + i;
        float4 c0 = *(const float4*)&csL[node * 8];
        float4 c1 = *(const float4*)&csL[node * 8 + 4];
        float a0 = bu0, a1 = bu1;
        a0 = fmaf(c0.x, wu0[0], a0); a1 = fmaf(c0.x, wu1[0], a1);
        a0 = fmaf(c0.y, wu0[1], a0); a1 = fmaf(c0.y, wu1[1], a1);
        a0 = fmaf(c0.z, wu0[2], a0); a1 = fmaf(c0.z, wu1[2], a1);
        a0 = fmaf(c0.w, wu0[3], a0); a1 = fmaf(c0.w, wu1[3], a1);
        a0 = fmaf(c1.x, wu0[4], a0); a1 = fmaf(c1.x, wu1[4], a1);
        a0 = fmaf(c1.y, wu0[5], a0); a1 = fmaf(c1.y, wu1[5], a1);
        a0 = fmaf(c1.z, wu0[6], a0); a1 = fmaf(c1.z, wu1[6], a1);
        union { unsigned int u; bf16 h[2]; } pk;
        pk.h[0] = (bf16)ftanh(a0);
        pk.h[1] = (bf16)ftanh(a1);
        dst[(drow + node) * 64 + cp] = pk.u;
    }
}

// ---------- launches 2,3: k_inner (j=11, j=10), now 8 blocks/CU ----------
__global__ __launch_bounds__(256, 8) void k_inner(
    const int2* __restrict__ children, const float* __restrict__ contents,
    const float* __restrict__ w_u, const float* __restrict__ b_u,
    const bf16* __restrict__ wb, const float* __restrict__ b_h,
    const bf16* __restrict__ emb_next, bf16* __restrict__ out_b)
{
    __shared__ bf16 xs[64 * XSTR];
    __shared__ int2 ch_s[64];
    __shared__ float cs[64 * 8];
    const int t = threadIdx.x;
    const int block0 = blockIdx.x * 64;
    if (t < 64) ch_s[t] = children[block0 + t];
    if (t < 112){
        float4 v = ((const float4*)(contents + (size_t)block0 * NF))[t];
        int e = t * 4;
        float vv[4] = {v.x, v.y, v.z, v.w};
        #pragma unroll
        for (int r = 0; r < 4; ++r){ int ee = e + r; cs[(ee/7)*8 + (ee%7)] = vv[r]; }
    }
    const int cp = t & 63;
    const int quarter = t >> 6;
    float wu0[NF], wu1[NF];
    {
        const float* w0 = w_u + (size_t)(2 * cp) * NF;
        #pragma unroll
        for (int f = 0; f < NF; ++f){ wu0[f] = w0[f]; wu1[f] = w0[NF + f]; }
    }
    const float bu0 = b_u[2 * cp], bu1 = b_u[2 * cp + 1];
    const int lane = t & 63;
    const int ct = t >> 6;
    const int m = lane & 31;
    const int q = lane >> 5;
    floatx16 acc0 = {0,0,0,0,0,0,0,0,0,0,0,0,0,0,0,0};
    floatx16 acc1 = {0,0,0,0,0,0,0,0,0,0,0,0,0,0,0,0};
    const bf16* bq = wb + ((size_t)(ct * 32 + m) * 384 + q * 8);
    #pragma unroll 1
    for (int p = 0; p < 3; ++p){
        __syncthreads();
        if (p < 2){
            #pragma unroll
            for (int r = 0; r < 4; ++r){
                int task = r * 256 + t;
                int i = task >> 4, part = task & 15;
                int row = (p == 0) ? ch_s[i].x : ch_s[i].y;
                uint4 v = *(const uint4*)(emb_next + (size_t)row * NH + part * 8);
                *(uint4*)&xs[i * XSTR + part * 8] = v;
            }
        } else {
            #pragma unroll 4
            for (int i = 0; i < 16; ++i){
                int node = quarter * 16 + i;
                float4 c0 = *(const float4*)&cs[node * 8];
                float4 c1 = *(const float4*)&cs[node * 8 + 4];
                float a0 = bu0, a1 = bu1;
                a0 = fmaf(c0.x, wu0[0], a0); a1 = fmaf(c0.x, wu1[0], a1);
                a0 = fmaf(c0.y, wu0[1], a0); a1 = fmaf(c0.y, wu1[1], a1);
                a0 = fmaf(c0.z, wu0[2], a0); a1 = fmaf(c0.z, wu1[2], a1);
                a0 = fmaf(c0.w, wu0[3], a0); a1 = fmaf(c0.w, wu1[3], a1);
                a0 = fmaf(c1.x, wu0[4], a0); a1 = fmaf(c1.x, wu1[4], a1);
                a0 = fmaf(c1.y, wu0[5], a0); a1 = fmaf(c1.y, wu1[5], a1);
                a0 = fmaf(c1.z, wu0[6], a0); a1 = fmaf(c1.z, wu1[6], a1);
                union { unsigned int u; bf16 h[2]; } pk;
                pk.h[0] = (bf16)ftanh(a0);
                pk.h[1] = (bf16)ftanh(a1);
                ((unsigned int*)xs)[node * (XSTR / 2) + cp] = pk.u;
            }
        }
        bf16x8 bfr[8];
        #pragma unroll
        for (int kk = 0; kk < 8; ++kk)
            bfr[kk] = *(const bf16x8*)(bq + p * 128 + kk * 16);
        __syncthreads();
        const bf16* xa = &xs[m * XSTR + q * 8];
        #pragma unroll
        for (int kk = 0; kk < 8; ++kk){
            bf16x8 a0 = *(const bf16x8*)(xa + kk * 16);
            bf16x8 a1 = *(const bf16x8*)(xa + kk * 16 + 32 * XSTR);
            acc0 = __builtin_amdgcn_mfma_f32_32x32x16_bf16(a0, bfr[kk], acc0, 0, 0, 0);
            acc1 = __builtin_amdgcn_mfma_f32_32x32x16_bf16(a1, bfr[kk], acc1, 0, 0, 0);
        }
    }
    const int colg = ct * 32 + m;
    const float bv = b_h[colg];
    #pragma unroll
    for (int nt = 0; nt < 2; ++nt){
        const floatx16* accp = nt ? &acc1 : &acc0;
        #pragma unroll
        for (int r = 0; r < 16; ++r){
            int row  = (r & 3) + 8 * (r >> 2) + 4 * q;
            int node = block0 + nt * 32 + row;
            out_b[(size_t)node * NH + colg] = (bf16)ftanh((*accp)[r] + bv);
        }
    }
}

// ---------- launch 4: levels 9..4, 1024 subtree blocks ----------
__global__ __launch_bounds__(256, 4) void k_tailA(
    const int* __restrict__ ids_A, const bf16* __restrict__ u_small,
    const bf16* __restrict__ wb, const float* __restrict__ b_h,
    const bf16* __restrict__ emb10, bf16* __restrict__ emb4)
{
    __shared__ bf16 xs[32 * XSTR3];    // 25088 B
    __shared__ bf16 embL[32 * 136];    // 8704 B
    __shared__ int ids[128];           // 512 B -> 34304 B, 4 blocks/CU
    const int t = threadIdx.x, root = blockIdx.x;
    const int ct = t >> 6, lane = t & 63, m = lane & 31, q = lane >> 5;
    const float bv = b_h[ct * 32 + m];
    if (t < 32) ((uint4*)ids)[t] = ((const uint4*)(ids_A + root * 128))[t];
    __syncthreads();
    const bf16* bq = wb + ((size_t)(ct * 32 + m) * 384 + q * 8);

    #pragma unroll 1
    for (int l = 9; l >= 4; --l){
        const int n = 1 << (l - 4);
        // hL/hR -> xs cols 0..255 (bottom level reads emb10, others read embL)
        #pragma unroll 1
        for (int r = 0; r < 4; ++r){
            int task = r * 256 + t;
            if (task < n * 32){
                int i = task >> 5, half = (task >> 4) & 1, part = task & 15;
                uint4 v;
                if (l == 9) v = *(const uint4*)(emb10 + (size_t)ids[63 + 2*i + half] * NH + part * 8);
                else        v = *(uint4*)&embL[(2*i + half) * 136 + part * 8];
                *(uint4*)&xs[i * XSTR3 + half * 128 + part * 8] = v;
            }
        }
        // u -> xs cols 256..383
        #pragma unroll 1
        for (int r = 0; r < 2; ++r){
            int task = r * 256 + t;
            if (task < n * 16){
                int i = task >> 4, part = task & 15;
                size_t row = (size_t)64 * ((1u << l) - 1) + ids[(n - 1) + i];
                *(uint4*)&xs[i * XSTR3 + 256 + part * 8] =
                    *(const uint4*)(u_small + row * NH + part * 8);
            }
        }
        __syncthreads();
        floatx16 accs[3];
        #pragma unroll
        for (int g = 0; g < 3; ++g) accs[g] = (floatx16){0,0,0,0,0,0,0,0,0,0,0,0,0,0,0,0};
        const bf16* xa = &xs[m * XSTR3 + q * 8];
        #pragma unroll
        for (int grp = 0; grp < 3; ++grp){
            bf16x8 bfr[8];
            #pragma unroll
            for (int kk = 0; kk < 8; ++kk)
                bfr[kk] = *(const bf16x8*)(bq + grp * 128 + kk * 16);
            #pragma unroll
            for (int kk = 0; kk < 8; ++kk){
                bf16x8 a0 = *(const bf16x8*)(xa + grp * 128 + kk * 16);
                accs[grp] = __builtin_amdgcn_mfma_f32_32x32x16_bf16(a0, bfr[kk], accs[grp], 0, 0, 0);
            }
        }
        floatx16 acc = accs[0] + accs[1] + accs[2];
        __syncthreads();   // all xs/embL reads done
        #pragma unroll
        for (int r = 0; r < 16; ++r){
            int row = (r & 3) + 8 * (r >> 2) + 4 * q;
            if (row < n){
                float v = ftanh(acc[r] + bv);
                if (l > 4) embL[row * 136 + ct * 32 + m] = (bf16)v;
                else       emb4[(size_t)root * NH + ct * 32 + m] = (bf16)v;
            }
        }
        __syncthreads();   // embL visible for next level's staging
    }
}

// ---------- launch 5: levels 3..0, 64 subtree blocks -> d_out ----------
__global__ __launch_bounds__(256, 4) void k_tailB(
    const int* __restrict__ ids_B, const bf16* __restrict__ u_small,
    const bf16* __restrict__ wb, const float* __restrict__ b_h,
    const bf16* __restrict__ emb4, float* __restrict__ out_f)
{
    __shared__ bf16 xs[8 * XSTR3];
    __shared__ bf16 embL[8 * 136];
    __shared__ int ids[32];
    const int t = threadIdx.x, root = blockIdx.x;
    const int ct = t >> 6, lane = t & 63, m = lane & 31, q = lane >> 5;
    const float bv = b_h[ct * 32 + m];
    if (t < 8) ((uint4*)ids)[t] = ((const uint4*)(ids_B + root * 32))[t];
    __syncthreads();
    const bf16* bq = wb + ((size_t)(ct * 32 + m) * 384 + q * 8);

    #pragma unroll 1
    for (int l = 3; l >= 0; --l){
        const int n = 1 << l;
        {
            int task = t;                        // n*32 <= 256
            if (task < n * 32){
                int i = task >> 5, half = (task >> 4) & 1, part = task & 15;
                uint4 v;
                if (l == 3) v = *(const uint4*)(emb4 + (size_t)ids[15 + 2*i + half] * NH + part * 8);
                else        v = *(uint4*)&embL[(2*i + half) * 136 + part * 8];
                *(uint4*)&xs[i * XSTR3 + half * 128 + part * 8] = v;
            }
            if (task < n * 16){
                int i = task >> 4, part = task & 15;
                size_t row = (size_t)64 * ((1u << l) - 1) + ids[(n - 1) + i];
                *(uint4*)&xs[i * XSTR3 + 256 + part * 8] =
                    *(const uint4*)(u_small + row * NH + part * 8);
            }
        }
        __syncthreads();
        floatx16 accs[3];
        #pragma unroll
        for (int g = 0; g < 3; ++g) accs[g] = (floatx16){0,0,0,0,0,0,0,0,0,0,0,0,0,0,0,0};
        const bf16* xa = &xs[m * XSTR3 + q * 8];
        #pragma unroll
        for (int grp = 0; grp < 3; ++grp){
            bf16x8 bfr[8];
            #pragma unroll
            for (int kk = 0; kk < 8; ++kk)
                bfr[kk] = *(const bf16x8*)(bq + grp * 128 + kk * 16);
            #pragma unroll
            for (int kk = 0; kk < 8; ++kk){
                bf16x8 a0 = *(const bf16x8*)(xa + grp * 128 + kk * 16);
                accs[grp] = __builtin_amdgcn_mfma_f32_32x32x16_bf16(a0, bfr[kk], accs[grp], 0, 0, 0);
            }
        }
        floatx16 acc = accs[0] + accs[1] + accs[2];
        __syncthreads();
        #pragma unroll
        for (int r = 0; r < 16; ++r){
            int row = (r & 3) + 8 * (r >> 2) + 4 * q;
            if (row < n){
                float v = ftanh(acc[r] + bv);
                if (l > 0) embL[row * 136 + ct * 32 + m] = (bf16)v;
                else       out_f[(size_t)root * NH + ct * 32 + m] = v;
            }
        }
        __syncthreads();
    }
}

// ---------- launcher ----------
extern "C" void kernel_launch(void* const* d_in, const int* in_sizes, int n_in,
                              void* d_out, int out_size, void* d_ws, size_t ws_size,
                              hipStream_t stream){
    const float* contents = (const float*)d_in[0];
    const int2*  children = (const int2*)d_in[1];
    const float* w_u      = (const float*)d_in[2];
    const float* b_u      = (const float*)d_in[3];
    const float* w_h      = (const float*)d_in[4];
    const float* b_h      = (const float*)d_in[5];
    float* outf = (float*)d_out;

    // ws: embA 67.1MB | embB 33.6MB | wb 96KB | u_small 16.8MB | ids_A 512KB | ids_B 8KB
    bf16* embA    = (bf16*)d_ws;
    bf16* embB    = embA + (size_t)NLEAF * NH;
    bf16* wb      = embB + (size_t)131072 * NH;
    bf16* u_small = wb + (size_t)NH * 384;
    int*  ids_A   = (int*)(u_small + (size_t)65536 * NH);
    int*  ids_B   = ids_A + 1024 * 128;

    hipLaunchKernelGGL(k_leaf, dim3(2565), dim3(256), 0, stream,
                       contents, children, w_u, b_u, w_h,
                       (unsigned int*)embA, (unsigned int*)u_small, wb, ids_A, ids_B);
    // j=11: emb12(embA) -> emb11(embB). INNER_OFF[11] rows = 131008
    hipLaunchKernelGGL(k_inner, dim3(2048), dim3(256), 0, stream,
                       children + 131008, contents + (size_t)131008 * NF,
                       w_u, b_u, wb, b_h, embA, embB);
    // j=10: emb11(embB) -> emb10(embA rows [0,65536)). INNER_OFF[10] = 65472
    hipLaunchKernelGGL(k_inner, dim3(1024), dim3(256), 0, stream,
                       children + 65472, contents + (size_t)65472 * NF,
                       w_u, b_u, wb, b_h, embB, embA);
    // levels 9..4: emb10 = embA -> emb4 = embB rows [0,1024)
    hipLaunchKernelGGL(k_tailA, dim3(1024), dim3(256), 0, stream,
                       ids_A, u_small, wb, b_h, embA, embB);
    // levels 3..0: emb4 = embB -> d_out
    hipLaunchKernelGGL(k_tailB, dim3(64), dim3(256), 0, stream,
                       ids_B, u_small, wb, b_h, embB, outf);
}

// Round 9
// 251.799 us; speedup vs baseline: 1.7623x; 1.7623x over previous
//
#include <hip/hip_runtime.h>
#include <hip/hip_bf16.h>

// GRNN tree transform v6.1: v6 with the k_inner launch-bounds regression fixed.
// __launch_bounds__(256,8) capped VGPR -> accumulator spills to scratch
// (hbm_bytes 70->736 MB, 49->254 us). Reverted to (256,4) (VGPR 52, no spill).
//  1. k_leaf: leaf emb + u_small(levels 0..9) + w_h cast + ids BFS precompute
//  2. k_inner j=11   3. k_inner j=10
//  4. k_tailA: levels 9..4, 1024 level-4 subtrees (ids precomputed, flat load)
//  5. k_tailB: levels 3..0, 64 level-0 subtrees -> d_out

#define NF 7
#define NH 128
#define NLEAF 262144
#define XSTR 136      // k_inner xs stride (bf16)
#define XSTR3 392     // tail xs stride: 384 + 8 pad

typedef __bf16 bf16;
typedef __bf16 bf16x8 __attribute__((ext_vector_type(8)));
typedef float floatx16 __attribute__((ext_vector_type(16)));

__device__ __forceinline__ float ftanh(float x){
    float e = __expf(2.0f * x);
    return 1.0f - __fdividef(2.0f, e + 1.0f);
}

// ---------- launch 1: leaf emb + u_small + wcast + ids BFS ----------
__global__ __launch_bounds__(256) void k_leaf(
    const float* __restrict__ contents, const int2* __restrict__ children,
    const float* __restrict__ w_u, const float* __restrict__ b_u,
    const float* __restrict__ w_h,
    unsigned int* __restrict__ embA_u32, unsigned int* __restrict__ usm_u32,
    bf16* __restrict__ wb, int* __restrict__ ids_A, int* __restrict__ ids_B)
{
    const int t = threadIdx.x;
    const int b = blockIdx.x;

    if (b >= 2560){
        if (b < 2564){
            int root = (b - 2560) * 256 + t;           // 0..1023
            int* base = ids_A + root * 128;
            const int2* ch4 = children + 960;
            const int2* ch5 = children + 1984;
            const int2* ch6 = children + 4032;
            const int2* ch7 = children + 8128;
            const int2* ch8 = children + 16320;
            const int2* ch9 = children + 32704;
            int l5[2], l6[4], l7[8], l8[16], l9[32];
            { int2 c = ch4[root]; l5[0] = c.x; l5[1] = c.y; }
            #pragma unroll
            for (int k = 0; k < 2; ++k){ int2 c = ch5[l5[k]]; l6[2*k] = c.x; l6[2*k+1] = c.y; }
            #pragma unroll
            for (int k = 0; k < 4; ++k){ int2 c = ch6[l6[k]]; l7[2*k] = c.x; l7[2*k+1] = c.y; }
            #pragma unroll
            for (int k = 0; k < 8; ++k){ int2 c = ch7[l7[k]]; l8[2*k] = c.x; l8[2*k+1] = c.y; }
            #pragma unroll
            for (int k = 0; k < 16; ++k){ int2 c = ch8[l8[k]]; l9[2*k] = c.x; l9[2*k+1] = c.y; }
            base[0] = root;
            base[1] = l5[0]; base[2] = l5[1];
            #pragma unroll
            for (int k = 0; k < 4; ++k)  base[3 + k]  = l6[k];
            #pragma unroll
            for (int k = 0; k < 8; ++k)  base[7 + k]  = l7[k];
            #pragma unroll
            for (int k = 0; k < 16; ++k) base[15 + k] = l8[k];
            #pragma unroll
            for (int k = 0; k < 32; ++k) base[31 + k] = l9[k];
            #pragma unroll
            for (int k = 0; k < 32; ++k){
                int2 c = ch9[l9[k]];
                base[63 + 2*k] = c.x; base[64 + 2*k] = c.y;
            }
        } else if (t < 64){
            int root = t;
            int* base = ids_B + root * 32;
            const int2* ch0 = children;
            const int2* ch1 = children + 64;
            const int2* ch2 = children + 192;
            const int2* ch3 = children + 448;
            int l1[2], l2[4], l3[8];
            { int2 c = ch0[root]; l1[0] = c.x; l1[1] = c.y; }
            #pragma unroll
            for (int k = 0; k < 2; ++k){ int2 c = ch1[l1[k]]; l2[2*k] = c.x; l2[2*k+1] = c.y; }
            #pragma unroll
            for (int k = 0; k < 4; ++k){ int2 c = ch2[l2[k]]; l3[2*k] = c.x; l3[2*k+1] = c.y; }
            base[0] = root;
            base[1] = l1[0]; base[2] = l1[1];
            #pragma unroll
            for (int k = 0; k < 4; ++k) base[3 + k] = l2[k];
            #pragma unroll
            for (int k = 0; k < 8; ++k) base[7 + k] = l3[k];
            #pragma unroll
            for (int k = 0; k < 8; ++k){
                int2 c = ch3[l3[k]];
                base[15 + 2*k] = c.x; base[16 + 2*k] = c.y;
            }
        }
        return;
    }

    __shared__ float csL[128 * 8];
    if (b < 192) wb[b * 256 + t] = (bf16)w_h[b * 256 + t];

    const int leaf = (b < 2048);
    const size_t srow = leaf ? (262080 + (size_t)b * 128) : ((size_t)(b - 2048) * 128);
    unsigned int* dst = leaf ? embA_u32 : usm_u32;
    const size_t drow = leaf ? ((size_t)b * 128) : ((size_t)(b - 2048) * 128);

    if (t < 224){
        float4 v = ((const float4*)(contents + srow * NF))[t];
        int e = t * 4;
        float vv[4] = {v.x, v.y, v.z, v.w};
        #pragma unroll
        for (int r = 0; r < 4; ++r){ int ee = e + r; csL[(ee/7)*8 + (ee%7)] = vv[r]; }
    }
    const int cp = t & 63;
    const int quarter = t >> 6;
    float wu0[NF], wu1[NF];
    const float* w0 = w_u + (size_t)(2 * cp) * NF;
    #pragma unroll
    for (int f = 0; f < NF; ++f){ wu0[f] = w0[f]; wu1[f] = w0[NF + f]; }
    const float bu0 = b_u[2 * cp], bu1 = b_u[2 * cp + 1];
    __syncthreads();
    #pragma unroll 4
    for (int i = 0; i < 32; ++i){
        int node = quarter * 32 + i;
        float4 c0 = *(const float4*)&csL[node * 8];
        float4 c1 = *(const float4*)&csL[node * 8 + 4];
        float a0 = bu0, a1 = bu1;
        a0 = fmaf(c0.x, wu0[0], a0); a1 = fmaf(c0.x, wu1[0], a1);
        a0 = fmaf(c0.y, wu0[1], a0); a1 = fmaf(c0.y, wu1[1], a1);
        a0 = fmaf(c0.z, wu0[2], a0); a1 = fmaf(c0.z, wu1[2], a1);
        a0 = fmaf(c0.w, wu0[3], a0); a1 = fmaf(c0.w, wu1[3], a1);
        a0 = fmaf(c1.x, wu0[4], a0); a1 = fmaf(c1.x, wu1[4], a1);
        a0 = fmaf(c1.y, wu0[5], a0); a1 = fmaf(c1.y, wu1[5], a1);
        a0 = fmaf(c1.z, wu0[6], a0); a1 = fmaf(c1.z, wu1[6], a1);
        union { unsigned int u; bf16 h[2]; } pk;
        pk.h[0] = (bf16)ftanh(a0);
        pk.h[1] = (bf16)ftanh(a1);
        dst[(drow + node) * 64 + cp] = pk.u;
    }
}

// ---------- launches 2,3: k_inner (j=11, j=10) — (256,4), VGPR 52, no spill ----------
__global__ __launch_bounds__(256, 4) void k_inner(
    const int2* __restrict__ children, const float* __restrict__ contents,
    const float* __restrict__ w_u, const float* __restrict__ b_u,
    const bf16* __restrict__ wb, const float* __restrict__ b_h,
    const bf16* __restrict__ emb_next, bf16* __restrict__ out_b)
{
    __shared__ bf16 xs[64 * XSTR];
    __shared__ int2 ch_s[64];
    __shared__ float cs[64 * 8];
    const int t = threadIdx.x;
    const int block0 = blockIdx.x * 64;
    if (t < 64) ch_s[t] = children[block0 + t];
    if (t < 112){
        float4 v = ((const float4*)(contents + (size_t)block0 * NF))[t];
        int e = t * 4;
        float vv[4] = {v.x, v.y, v.z, v.w};
        #pragma unroll
        for (int r = 0; r < 4; ++r){ int ee = e + r; cs[(ee/7)*8 + (ee%7)] = vv[r]; }
    }
    const int cp = t & 63;
    const int quarter = t >> 6;
    float wu0[NF], wu1[NF];
    {
        const float* w0 = w_u + (size_t)(2 * cp) * NF;
        #pragma unroll
        for (int f = 0; f < NF; ++f){ wu0[f] = w0[f]; wu1[f] = w0[NF + f]; }
    }
    const float bu0 = b_u[2 * cp], bu1 = b_u[2 * cp + 1];
    const int lane = t & 63;
    const int ct = t >> 6;
    const int m = lane & 31;
    const int q = lane >> 5;
    floatx16 acc0 = {0,0,0,0,0,0,0,0,0,0,0,0,0,0,0,0};
    floatx16 acc1 = {0,0,0,0,0,0,0,0,0,0,0,0,0,0,0,0};
    const bf16* bq = wb + ((size_t)(ct * 32 + m) * 384 + q * 8);
    #pragma unroll 1
    for (int p = 0; p < 3; ++p){
        __syncthreads();
        if (p < 2){
            #pragma unroll
            for (int r = 0; r < 4; ++r){
                int task = r * 256 + t;
                int i = task >> 4, part = task & 15;
                int row = (p == 0) ? ch_s[i].x : ch_s[i].y;
                uint4 v = *(const uint4*)(emb_next + (size_t)row * NH + part * 8);
                *(uint4*)&xs[i * XSTR + part * 8] = v;
            }
        } else {
            #pragma unroll 4
            for (int i = 0; i < 16; ++i){
                int node = quarter * 16 + i;
                float4 c0 = *(const float4*)&cs[node * 8];
                float4 c1 = *(const float4*)&cs[node * 8 + 4];
                float a0 = bu0, a1 = bu1;
                a0 = fmaf(c0.x, wu0[0], a0); a1 = fmaf(c0.x, wu1[0], a1);
                a0 = fmaf(c0.y, wu0[1], a0); a1 = fmaf(c0.y, wu1[1], a1);
                a0 = fmaf(c0.z, wu0[2], a0); a1 = fmaf(c0.z, wu1[2], a1);
                a0 = fmaf(c0.w, wu0[3], a0); a1 = fmaf(c0.w, wu1[3], a1);
                a0 = fmaf(c1.x, wu0[4], a0); a1 = fmaf(c1.x, wu1[4], a1);
                a0 = fmaf(c1.y, wu0[5], a0); a1 = fmaf(c1.y, wu1[5], a1);
                a0 = fmaf(c1.z, wu0[6], a0); a1 = fmaf(c1.z, wu1[6], a1);
                union { unsigned int u; bf16 h[2]; } pk;
                pk.h[0] = (bf16)ftanh(a0);
                pk.h[1] = (bf16)ftanh(a1);
                ((unsigned int*)xs)[node * (XSTR / 2) + cp] = pk.u;
            }
        }
        bf16x8 bfr[8];
        #pragma unroll
        for (int kk = 0; kk < 8; ++kk)
            bfr[kk] = *(const bf16x8*)(bq + p * 128 + kk * 16);
        __syncthreads();
        const bf16* xa = &xs[m * XSTR + q * 8];
        #pragma unroll
        for (int kk = 0; kk < 8; ++kk){
            bf16x8 a0 = *(const bf16x8*)(xa + kk * 16);
            bf16x8 a1 = *(const bf16x8*)(xa + kk * 16 + 32 * XSTR);
            acc0 = __builtin_amdgcn_mfma_f32_32x32x16_bf16(a0, bfr[kk], acc0, 0, 0, 0);
            acc1 = __builtin_amdgcn_mfma_f32_32x32x16_bf16(a1, bfr[kk], acc1, 0, 0, 0);
        }
    }
    const int colg = ct * 32 + m;
    const float bv = b_h[colg];
    #pragma unroll
    for (int nt = 0; nt < 2; ++nt){
        const floatx16* accp = nt ? &acc1 : &acc0;
        #pragma unroll
        for (int r = 0; r < 16; ++r){
            int row  = (r & 3) + 8 * (r >> 2) + 4 * q;
            int node = block0 + nt * 32 + row;
            out_b[(size_t)node * NH + colg] = (bf16)ftanh((*accp)[r] + bv);
        }
    }
}

// ---------- launch 4: levels 9..4, 1024 subtree blocks ----------
__global__ __launch_bounds__(256, 4) void k_tailA(
    const int* __restrict__ ids_A, const bf16* __restrict__ u_small,
    const bf16* __restrict__ wb, const float* __restrict__ b_h,
    const bf16* __restrict__ emb10, bf16* __restrict__ emb4)
{
    __shared__ bf16 xs[32 * XSTR3];    // 25088 B
    __shared__ bf16 embL[32 * 136];    // 8704 B
    __shared__ int ids[128];           // 512 B -> 34304 B, 4 blocks/CU
    const int t = threadIdx.x, root = blockIdx.x;
    const int ct = t >> 6, lane = t & 63, m = lane & 31, q = lane >> 5;
    const float bv = b_h[ct * 32 + m];
    if (t < 32) ((uint4*)ids)[t] = ((const uint4*)(ids_A + root * 128))[t];
    __syncthreads();
    const bf16* bq = wb + ((size_t)(ct * 32 + m) * 384 + q * 8);

    #pragma unroll 1
    for (int l = 9; l >= 4; --l){
        const int n = 1 << (l - 4);
        #pragma unroll 1
        for (int r = 0; r < 4; ++r){
            int task = r * 256 + t;
            if (task < n * 32){
                int i = task >> 5, half = (task >> 4) & 1, part = task & 15;
                uint4 v;
                if (l == 9) v = *(const uint4*)(emb10 + (size_t)ids[63 + 2*i + half] * NH + part * 8);
                else        v = *(uint4*)&embL[(2*i + half) * 136 + part * 8];
                *(uint4*)&xs[i * XSTR3 + half * 128 + part * 8] = v;
            }
        }
        #pragma unroll 1
        for (int r = 0; r < 2; ++r){
            int task = r * 256 + t;
            if (task < n * 16){
                int i = task >> 4, part = task & 15;
                size_t row = (size_t)64 * ((1u << l) - 1) + ids[(n - 1) + i];
                *(uint4*)&xs[i * XSTR3 + 256 + part * 8] =
                    *(const uint4*)(u_small + row * NH + part * 8);
            }
        }
        __syncthreads();
        floatx16 accs[3];
        #pragma unroll
        for (int g = 0; g < 3; ++g) accs[g] = (floatx16){0,0,0,0,0,0,0,0,0,0,0,0,0,0,0,0};
        const bf16* xa = &xs[m * XSTR3 + q * 8];
        #pragma unroll
        for (int grp = 0; grp < 3; ++grp){
            bf16x8 bfr[8];
            #pragma unroll
            for (int kk = 0; kk < 8; ++kk)
                bfr[kk] = *(const bf16x8*)(bq + grp * 128 + kk * 16);
            #pragma unroll
            for (int kk = 0; kk < 8; ++kk){
                bf16x8 a0 = *(const bf16x8*)(xa + grp * 128 + kk * 16);
                accs[grp] = __builtin_amdgcn_mfma_f32_32x32x16_bf16(a0, bfr[kk], accs[grp], 0, 0, 0);
            }
        }
        floatx16 acc = accs[0] + accs[1] + accs[2];
        __syncthreads();
        #pragma unroll
        for (int r = 0; r < 16; ++r){
            int row = (r & 3) + 8 * (r >> 2) + 4 * q;
            if (row < n){
                float v = ftanh(acc[r] + bv);
                if (l > 4) embL[row * 136 + ct * 32 + m] = (bf16)v;
                else       emb4[(size_t)root * NH + ct * 32 + m] = (bf16)v;
            }
        }
        __syncthreads();
    }
}

// ---------- launch 5: levels 3..0, 64 subtree blocks -> d_out ----------
__global__ __launch_bounds__(256, 4) void k_tailB(
    const int* __restrict__ ids_B, const bf16* __restrict__ u_small,
    const bf16* __restrict__ wb, const float* __restrict__ b_h,
    const bf16* __restrict__ emb4, float* __restrict__ out_f)
{
    __shared__ bf16 xs[8 * XSTR3];
    __shared__ bf16 embL[8 * 136];
    __shared__ int ids[32];
    const int t = threadIdx.x, root = blockIdx.x;
    const int ct = t >> 6, lane = t & 63, m = lane & 31, q = lane >> 5;
    const float bv = b_h[ct * 32 + m];
    if (t < 8) ((uint4*)ids)[t] = ((const uint4*)(ids_B + root * 32))[t];
    __syncthreads();
    const bf16* bq = wb + ((size_t)(ct * 32 + m) * 384 + q * 8);

    #pragma unroll 1
    for (int l = 3; l >= 0; --l){
        const int n = 1 << l;
        {
            int task = t;
            if (task < n * 32){
                int i = task >> 5, half = (task >> 4) & 1, part = task & 15;
                uint4 v;
                if (l == 3) v = *(const uint4*)(emb4 + (size_t)ids[15 + 2*i + half] * NH + part * 8);
                else        v = *(uint4*)&embL[(2*i + half) * 136 + part * 8];
                *(uint4*)&xs[i * XSTR3 + half * 128 + part * 8] = v;
            }
            if (task < n * 16){
                int i = task >> 4, part = task & 15;
                size_t row = (size_t)64 * ((1u << l) - 1) + ids[(n - 1) + i];
                *(uint4*)&xs[i * XSTR3 + 256 + part * 8] =
                    *(const uint4*)(u_small + row * NH + part * 8);
            }
        }
        __syncthreads();
        floatx16 accs[3];
        #pragma unroll
        for (int g = 0; g < 3; ++g) accs[g] = (floatx16){0,0,0,0,0,0,0,0,0,0,0,0,0,0,0,0};
        const bf16* xa = &xs[m * XSTR3 + q * 8];
        #pragma unroll
        for (int grp = 0; grp < 3; ++grp){
            bf16x8 bfr[8];
            #pragma unroll
            for (int kk = 0; kk < 8; ++kk)
                bfr[kk] = *(const bf16x8*)(bq + grp * 128 + kk * 16);
            #pragma unroll
            for (int kk = 0; kk < 8; ++kk){
                bf16x8 a0 = *(const bf16x8*)(xa + grp * 128 + kk * 16);
                accs[grp] = __builtin_amdgcn_mfma_f32_32x32x16_bf16(a0, bfr[kk], accs[grp], 0, 0, 0);
            }
        }
        floatx16 acc = accs[0] + accs[1] + accs[2];
        __syncthreads();
        #pragma unroll
        for (int r = 0; r < 16; ++r){
            int row = (r & 3) + 8 * (r >> 2) + 4 * q;
            if (row < n){
                float v = ftanh(acc[r] + bv);
                if (l > 0) embL[row * 136 + ct * 32 + m] = (bf16)v;
                else       out_f[(size_t)root * NH + ct * 32 + m] = v;
            }
        }
        __syncthreads();
    }
}

// ---------- launcher ----------
extern "C" void kernel_launch(void* const* d_in, const int* in_sizes, int n_in,
                              void* d_out, int out_size, void* d_ws, size_t ws_size,
                              hipStream_t stream){
    const float* contents = (const float*)d_in[0];
    const int2*  children = (const int2*)d_in[1];
    const float* w_u      = (const float*)d_in[2];
    const float* b_u      = (const float*)d_in[3];
    const float* w_h      = (const float*)d_in[4];
    const float* b_h      = (const float*)d_in[5];
    float* outf = (float*)d_out;

    bf16* embA    = (bf16*)d_ws;
    bf16* embB    = embA + (size_t)NLEAF * NH;
    bf16* wb      = embB + (size_t)131072 * NH;
    bf16* u_small = wb + (size_t)NH * 384;
    int*  ids_A   = (int*)(u_small + (size_t)65536 * NH);
    int*  ids_B   = ids_A + 1024 * 128;

    hipLaunchKernelGGL(k_leaf, dim3(2565), dim3(256), 0, stream,
                       contents, children, w_u, b_u, w_h,
                       (unsigned int*)embA, (unsigned int*)u_small, wb, ids_A, ids_B);
    hipLaunchKernelGGL(k_inner, dim3(2048), dim3(256), 0, stream,
                       children + 131008, contents + (size_t)131008 * NF,
                       w_u, b_u, wb, b_h, embA, embB);
    hipLaunchKernelGGL(k_inner, dim3(1024), dim3(256), 0, stream,
                       children + 65472, contents + (size_t)65472 * NF,
                       w_u, b_u, wb, b_h, embB, embA);
    hipLaunchKernelGGL(k_tailA, dim3(1024), dim3(256), 0, stream,
                       ids_A, u_small, wb, b_h, embA, embB);
    hipLaunchKernelGGL(k_tailB, dim3(64), dim3(256), 0, stream,
                       ids_B, u_small, wb, b_h, embB, outf);
}

// Round 10
// 229.750 us; speedup vs baseline: 1.9314x; 1.0960x over previous
//
#include <hip/hip_runtime.h>
#include <hip/hip_bf16.h>

// GRNN tree transform v6.2: v6.1 with the TAIL spill fixed.
// Round-9 evidence: k_tailA WRITE_SIZE=41216 KB (expected 0.26 MB) + FETCH 2x
// ideal = accumulator scratch spill from __launch_bounds__(256,4) (128-reg cap
// on the unified VGPR/AGPR file; kernel needs ~110 VGPR + 48 acc).
// Fix: (256,2) on k_tailA/k_tailB (256-reg cap, no spill). k_inner stays (256,4)
// (VGPR 52 + 32 AGPR, proven spill-free).

#define NF 7
#define NH 128
#define NLEAF 262144
#define XSTR 136      // k_inner xs stride (bf16)
#define XSTR3 392     // tail xs stride: 384 + 8 pad

typedef __bf16 bf16;
typedef __bf16 bf16x8 __attribute__((ext_vector_type(8)));
typedef float floatx16 __attribute__((ext_vector_type(16)));

__device__ __forceinline__ float ftanh(float x){
    float e = __expf(2.0f * x);
    return 1.0f - __fdividef(2.0f, e + 1.0f);
}

// ---------- launch 1: leaf emb + u_small + wcast + ids BFS ----------
__global__ __launch_bounds__(256) void k_leaf(
    const float* __restrict__ contents, const int2* __restrict__ children,
    const float* __restrict__ w_u, const float* __restrict__ b_u,
    const float* __restrict__ w_h,
    unsigned int* __restrict__ embA_u32, unsigned int* __restrict__ usm_u32,
    bf16* __restrict__ wb, int* __restrict__ ids_A, int* __restrict__ ids_B)
{
    const int t = threadIdx.x;
    const int b = blockIdx.x;

    if (b >= 2560){
        if (b < 2564){
            int root = (b - 2560) * 256 + t;           // 0..1023
            int* base = ids_A + root * 128;
            const int2* ch4 = children + 960;
            const int2* ch5 = children + 1984;
            const int2* ch6 = children + 4032;
            const int2* ch7 = children + 8128;
            const int2* ch8 = children + 16320;
            const int2* ch9 = children + 32704;
            int l5[2], l6[4], l7[8], l8[16], l9[32];
            { int2 c = ch4[root]; l5[0] = c.x; l5[1] = c.y; }
            #pragma unroll
            for (int k = 0; k < 2; ++k){ int2 c = ch5[l5[k]]; l6[2*k] = c.x; l6[2*k+1] = c.y; }
            #pragma unroll
            for (int k = 0; k < 4; ++k){ int2 c = ch6[l6[k]]; l7[2*k] = c.x; l7[2*k+1] = c.y; }
            #pragma unroll
            for (int k = 0; k < 8; ++k){ int2 c = ch7[l7[k]]; l8[2*k] = c.x; l8[2*k+1] = c.y; }
            #pragma unroll
            for (int k = 0; k < 16; ++k){ int2 c = ch8[l8[k]]; l9[2*k] = c.x; l9[2*k+1] = c.y; }
            base[0] = root;
            base[1] = l5[0]; base[2] = l5[1];
            #pragma unroll
            for (int k = 0; k < 4; ++k)  base[3 + k]  = l6[k];
            #pragma unroll
            for (int k = 0; k < 8; ++k)  base[7 + k]  = l7[k];
            #pragma unroll
            for (int k = 0; k < 16; ++k) base[15 + k] = l8[k];
            #pragma unroll
            for (int k = 0; k < 32; ++k) base[31 + k] = l9[k];
            #pragma unroll
            for (int k = 0; k < 32; ++k){
                int2 c = ch9[l9[k]];
                base[63 + 2*k] = c.x; base[64 + 2*k] = c.y;
            }
        } else if (t < 64){
            int root = t;
            int* base = ids_B + root * 32;
            const int2* ch0 = children;
            const int2* ch1 = children + 64;
            const int2* ch2 = children + 192;
            const int2* ch3 = children + 448;
            int l1[2], l2[4], l3[8];
            { int2 c = ch0[root]; l1[0] = c.x; l1[1] = c.y; }
            #pragma unroll
            for (int k = 0; k < 2; ++k){ int2 c = ch1[l1[k]]; l2[2*k] = c.x; l2[2*k+1] = c.y; }
            #pragma unroll
            for (int k = 0; k < 4; ++k){ int2 c = ch2[l2[k]]; l3[2*k] = c.x; l3[2*k+1] = c.y; }
            base[0] = root;
            base[1] = l1[0]; base[2] = l1[1];
            #pragma unroll
            for (int k = 0; k < 4; ++k) base[3 + k] = l2[k];
            #pragma unroll
            for (int k = 0; k < 8; ++k) base[7 + k] = l3[k];
            #pragma unroll
            for (int k = 0; k < 8; ++k){
                int2 c = ch3[l3[k]];
                base[15 + 2*k] = c.x; base[16 + 2*k] = c.y;
            }
        }
        return;
    }

    __shared__ float csL[128 * 8];
    if (b < 192) wb[b * 256 + t] = (bf16)w_h[b * 256 + t];

    const int leaf = (b < 2048);
    const size_t srow = leaf ? (262080 + (size_t)b * 128) : ((size_t)(b - 2048) * 128);
    unsigned int* dst = leaf ? embA_u32 : usm_u32;
    const size_t drow = leaf ? ((size_t)b * 128) : ((size_t)(b - 2048) * 128);

    if (t < 224){
        float4 v = ((const float4*)(contents + srow * NF))[t];
        int e = t * 4;
        float vv[4] = {v.x, v.y, v.z, v.w};
        #pragma unroll
        for (int r = 0; r < 4; ++r){ int ee = e + r; csL[(ee/7)*8 + (ee%7)] = vv[r]; }
    }
    const int cp = t & 63;
    const int quarter = t >> 6;
    float wu0[NF], wu1[NF];
    const float* w0 = w_u + (size_t)(2 * cp) * NF;
    #pragma unroll
    for (int f = 0; f < NF; ++f){ wu0[f] = w0[f]; wu1[f] = w0[NF + f]; }
    const float bu0 = b_u[2 * cp], bu1 = b_u[2 * cp + 1];
    __syncthreads();
    #pragma unroll 4
    for (int i = 0; i < 32; ++i){
        int node = quarter * 32 + i;
        float4 c0 = *(const float4*)&csL[node * 8];
        float4 c1 = *(const float4*)&csL[node * 8 + 4];
        float a0 = bu0, a1 = bu1;
        a0 = fmaf(c0.x, wu0[0], a0); a1 = fmaf(c0.x, wu1[0], a1);
        a0 = fmaf(c0.y, wu0[1], a0); a1 = fmaf(c0.y, wu1[1], a1);
        a0 = fmaf(c0.z, wu0[2], a0); a1 = fmaf(c0.z, wu1[2], a1);
        a0 = fmaf(c0.w, wu0[3], a0); a1 = fmaf(c0.w, wu1[3], a1);
        a0 = fmaf(c1.x, wu0[4], a0); a1 = fmaf(c1.x, wu1[4], a1);
        a0 = fmaf(c1.y, wu0[5], a0); a1 = fmaf(c1.y, wu1[5], a1);
        a0 = fmaf(c1.z, wu0[6], a0); a1 = fmaf(c1.z, wu1[6], a1);
        union { unsigned int u; bf16 h[2]; } pk;
        pk.h[0] = (bf16)ftanh(a0);
        pk.h[1] = (bf16)ftanh(a1);
        dst[(drow + node) * 64 + cp] = pk.u;
    }
}

// ---------- launches 2,3: k_inner (j=11, j=10) — (256,4), no spill ----------
__global__ __launch_bounds__(256, 4) void k_inner(
    const int2* __restrict__ children, const float* __restrict__ contents,
    const float* __restrict__ w_u, const float* __restrict__ b_u,
    const bf16* __restrict__ wb, const float* __restrict__ b_h,
    const bf16* __restrict__ emb_next, bf16* __restrict__ out_b)
{
    __shared__ bf16 xs[64 * XSTR];
    __shared__ int2 ch_s[64];
    __shared__ float cs[64 * 8];
    const int t = threadIdx.x;
    const int block0 = blockIdx.x * 64;
    if (t < 64) ch_s[t] = children[block0 + t];
    if (t < 112){
        float4 v = ((const float4*)(contents + (size_t)block0 * NF))[t];
        int e = t * 4;
        float vv[4] = {v.x, v.y, v.z, v.w};
        #pragma unroll
        for (int r = 0; r < 4; ++r){ int ee = e + r; cs[(ee/7)*8 + (ee%7)] = vv[r]; }
    }
    const int cp = t & 63;
    const int quarter = t >> 6;
    float wu0[NF], wu1[NF];
    {
        const float* w0 = w_u + (size_t)(2 * cp) * NF;
        #pragma unroll
        for (int f = 0; f < NF; ++f){ wu0[f] = w0[f]; wu1[f] = w0[NF + f]; }
    }
    const float bu0 = b_u[2 * cp], bu1 = b_u[2 * cp + 1];
    const int lane = t & 63;
    const int ct = t >> 6;
    const int m = lane & 31;
    const int q = lane >> 5;
    floatx16 acc0 = {0,0,0,0,0,0,0,0,0,0,0,0,0,0,0,0};
    floatx16 acc1 = {0,0,0,0,0,0,0,0,0,0,0,0,0,0,0,0};
    const bf16* bq = wb + ((size_t)(ct * 32 + m) * 384 + q * 8);
    #pragma unroll 1
    for (int p = 0; p < 3; ++p){
        __syncthreads();
        if (p < 2){
            #pragma unroll
            for (int r = 0; r < 4; ++r){
                int task = r * 256 + t;
                int i = task >> 4, part = task & 15;
                int row = (p == 0) ? ch_s[i].x : ch_s[i].y;
                uint4 v = *(const uint4*)(emb_next + (size_t)row * NH + part * 8);
                *(uint4*)&xs[i * XSTR + part * 8] = v;
            }
        } else {
            #pragma unroll 4
            for (int i = 0; i < 16; ++i){
                int node = quarter * 16 + i;
                float4 c0 = *(const float4*)&cs[node * 8];
                float4 c1 = *(const float4*)&cs[node * 8 + 4];
                float a0 = bu0, a1 = bu1;
                a0 = fmaf(c0.x, wu0[0], a0); a1 = fmaf(c0.x, wu1[0], a1);
                a0 = fmaf(c0.y, wu0[1], a0); a1 = fmaf(c0.y, wu1[1], a1);
                a0 = fmaf(c0.z, wu0[2], a0); a1 = fmaf(c0.z, wu1[2], a1);
                a0 = fmaf(c0.w, wu0[3], a0); a1 = fmaf(c0.w, wu1[3], a1);
                a0 = fmaf(c1.x, wu0[4], a0); a1 = fmaf(c1.x, wu1[4], a1);
                a0 = fmaf(c1.y, wu0[5], a0); a1 = fmaf(c1.y, wu1[5], a1);
                a0 = fmaf(c1.z, wu0[6], a0); a1 = fmaf(c1.z, wu1[6], a1);
                union { unsigned int u; bf16 h[2]; } pk;
                pk.h[0] = (bf16)ftanh(a0);
                pk.h[1] = (bf16)ftanh(a1);
                ((unsigned int*)xs)[node * (XSTR / 2) + cp] = pk.u;
            }
        }
        bf16x8 bfr[8];
        #pragma unroll
        for (int kk = 0; kk < 8; ++kk)
            bfr[kk] = *(const bf16x8*)(bq + p * 128 + kk * 16);
        __syncthreads();
        const bf16* xa = &xs[m * XSTR + q * 8];
        #pragma unroll
        for (int kk = 0; kk < 8; ++kk){
            bf16x8 a0 = *(const bf16x8*)(xa + kk * 16);
            bf16x8 a1 = *(const bf16x8*)(xa + kk * 16 + 32 * XSTR);
            acc0 = __builtin_amdgcn_mfma_f32_32x32x16_bf16(a0, bfr[kk], acc0, 0, 0, 0);
            acc1 = __builtin_amdgcn_mfma_f32_32x32x16_bf16(a1, bfr[kk], acc1, 0, 0, 0);
        }
    }
    const int colg = ct * 32 + m;
    const float bv = b_h[colg];
    #pragma unroll
    for (int nt = 0; nt < 2; ++nt){
        const floatx16* accp = nt ? &acc1 : &acc0;
        #pragma unroll
        for (int r = 0; r < 16; ++r){
            int row  = (r & 3) + 8 * (r >> 2) + 4 * q;
            int node = block0 + nt * 32 + row;
            out_b[(size_t)node * NH + colg] = (bf16)ftanh((*accp)[r] + bv);
        }
    }
}

// ---------- launch 4: levels 9..4, 1024 subtree blocks — (256,2): no spill ----------
__global__ __launch_bounds__(256, 2) void k_tailA(
    const int* __restrict__ ids_A, const bf16* __restrict__ u_small,
    const bf16* __restrict__ wb, const float* __restrict__ b_h,
    const bf16* __restrict__ emb10, bf16* __restrict__ emb4)
{
    __shared__ bf16 xs[32 * XSTR3];    // 25088 B
    __shared__ bf16 embL[32 * 136];    // 8704 B
    __shared__ int ids[128];           // 512 B -> 34304 B
    const int t = threadIdx.x, root = blockIdx.x;
    const int ct = t >> 6, lane = t & 63, m = lane & 31, q = lane >> 5;
    const float bv = b_h[ct * 32 + m];
    if (t < 32) ((uint4*)ids)[t] = ((const uint4*)(ids_A + root * 128))[t];
    __syncthreads();
    const bf16* bq = wb + ((size_t)(ct * 32 + m) * 384 + q * 8);

    #pragma unroll 1
    for (int l = 9; l >= 4; --l){
        const int n = 1 << (l - 4);
        #pragma unroll 1
        for (int r = 0; r < 4; ++r){
            int task = r * 256 + t;
            if (task < n * 32){
                int i = task >> 5, half = (task >> 4) & 1, part = task & 15;
                uint4 v;
                if (l == 9) v = *(const uint4*)(emb10 + (size_t)ids[63 + 2*i + half] * NH + part * 8);
                else        v = *(uint4*)&embL[(2*i + half) * 136 + part * 8];
                *(uint4*)&xs[i * XSTR3 + half * 128 + part * 8] = v;
            }
        }
        #pragma unroll 1
        for (int r = 0; r < 2; ++r){
            int task = r * 256 + t;
            if (task < n * 16){
                int i = task >> 4, part = task & 15;
                size_t row = (size_t)64 * ((1u << l) - 1) + ids[(n - 1) + i];
                *(uint4*)&xs[i * XSTR3 + 256 + part * 8] =
                    *(const uint4*)(u_small + row * NH + part * 8);
            }
        }
        __syncthreads();
        floatx16 accs[3];
        #pragma unroll
        for (int g = 0; g < 3; ++g) accs[g] = (floatx16){0,0,0,0,0,0,0,0,0,0,0,0,0,0,0,0};
        const bf16* xa = &xs[m * XSTR3 + q * 8];
        #pragma unroll
        for (int grp = 0; grp < 3; ++grp){
            bf16x8 bfr[8];
            #pragma unroll
            for (int kk = 0; kk < 8; ++kk)
                bfr[kk] = *(const bf16x8*)(bq + grp * 128 + kk * 16);
            #pragma unroll
            for (int kk = 0; kk < 8; ++kk){
                bf16x8 a0 = *(const bf16x8*)(xa + grp * 128 + kk * 16);
                accs[grp] = __builtin_amdgcn_mfma_f32_32x32x16_bf16(a0, bfr[kk], accs[grp], 0, 0, 0);
            }
        }
        floatx16 acc = accs[0] + accs[1] + accs[2];
        __syncthreads();
        #pragma unroll
        for (int r = 0; r < 16; ++r){
            int row = (r & 3) + 8 * (r >> 2) + 4 * q;
            if (row < n){
                float v = ftanh(acc[r] + bv);
                if (l > 4) embL[row * 136 + ct * 32 + m] = (bf16)v;
                else       emb4[(size_t)root * NH + ct * 32 + m] = (bf16)v;
            }
        }
        __syncthreads();
    }
}

// ---------- launch 5: levels 3..0, 64 subtree blocks -> d_out — (256,2) ----------
__global__ __launch_bounds__(256, 2) void k_tailB(
    const int* __restrict__ ids_B, const bf16* __restrict__ u_small,
    const bf16* __restrict__ wb, const float* __restrict__ b_h,
    const bf16* __restrict__ emb4, float* __restrict__ out_f)
{
    __shared__ bf16 xs[8 * XSTR3];
    __shared__ bf16 embL[8 * 136];
    __shared__ int ids[32];
    const int t = threadIdx.x, root = blockIdx.x;
    const int ct = t >> 6, lane = t & 63, m = lane & 31, q = lane >> 5;
    const float bv = b_h[ct * 32 + m];
    if (t < 8) ((uint4*)ids)[t] = ((const uint4*)(ids_B + root * 32))[t];
    __syncthreads();
    const bf16* bq = wb + ((size_t)(ct * 32 + m) * 384 + q * 8);

    #pragma unroll 1
    for (int l = 3; l >= 0; --l){
        const int n = 1 << l;
        {
            int task = t;
            if (task < n * 32){
                int i = task >> 5, half = (task >> 4) & 1, part = task & 15;
                uint4 v;
                if (l == 3) v = *(const uint4*)(emb4 + (size_t)ids[15 + 2*i + half] * NH + part * 8);
                else        v = *(uint4*)&embL[(2*i + half) * 136 + part * 8];
                *(uint4*)&xs[i * XSTR3 + half * 128 + part * 8] = v;
            }
            if (task < n * 16){
                int i = task >> 4, part = task & 15;
                size_t row = (size_t)64 * ((1u << l) - 1) + ids[(n - 1) + i];
                *(uint4*)&xs[i * XSTR3 + 256 + part * 8] =
                    *(const uint4*)(u_small + row * NH + part * 8);
            }
        }
        __syncthreads();
        floatx16 accs[3];
        #pragma unroll
        for (int g = 0; g < 3; ++g) accs[g] = (floatx16){0,0,0,0,0,0,0,0,0,0,0,0,0,0,0,0};
        const bf16* xa = &xs[m * XSTR3 + q * 8];
        #pragma unroll
        for (int grp = 0; grp < 3; ++grp){
            bf16x8 bfr[8];
            #pragma unroll
            for (int kk = 0; kk < 8; ++kk)
                bfr[kk] = *(const bf16x8*)(bq + grp * 128 + kk * 16);
            #pragma unroll
            for (int kk = 0; kk < 8; ++kk){
                bf16x8 a0 = *(const bf16x8*)(xa + grp * 128 + kk * 16);
                accs[grp] = __builtin_amdgcn_mfma_f32_32x32x16_bf16(a0, bfr[kk], accs[grp], 0, 0, 0);
            }
        }
        floatx16 acc = accs[0] + accs[1] + accs[2];
        __syncthreads();
        #pragma unroll
        for (int r = 0; r < 16; ++r){
            int row = (r & 3) + 8 * (r >> 2) + 4 * q;
            if (row < n){
                float v = ftanh(acc[r] + bv);
                if (l > 0) embL[row * 136 + ct * 32 + m] = (bf16)v;
                else       out_f[(size_t)root * NH + ct * 32 + m] = v;
            }
        }
        __syncthreads();
    }
}

// ---------- launcher ----------
extern "C" void kernel_launch(void* const* d_in, const int* in_sizes, int n_in,
                              void* d_out, int out_size, void* d_ws, size_t ws_size,
                              hipStream_t stream){
    const float* contents = (const float*)d_in[0];
    const int2*  children = (const int2*)d_in[1];
    const float* w_u      = (const float*)d_in[2];
    const float* b_u      = (const float*)d_in[3];
    const float* w_h      = (const float*)d_in[4];
    const float* b_h      = (const float*)d_in[5];
    float* outf = (float*)d_out;

    bf16* embA    = (bf16*)d_ws;
    bf16* embB    = embA + (size_t)NLEAF * NH;
    bf16* wb      = embB + (size_t)131072 * NH;
    bf16* u_small = wb + (size_t)NH * 384;
    int*  ids_A   = (int*)(u_small + (size_t)65536 * NH);
    int*  ids_B   = ids_A + 1024 * 128;

    hipLaunchKernelGGL(k_leaf, dim3(2565), dim3(256), 0, stream,
                       contents, children, w_u, b_u, w_h,
                       (unsigned int*)embA, (unsigned int*)u_small, wb, ids_A, ids_B);
    hipLaunchKernelGGL(k_inner, dim3(2048), dim3(256), 0, stream,
                       children + 131008, contents + (size_t)131008 * NF,
                       w_u, b_u, wb, b_h, embA, embB);
    hipLaunchKernelGGL(k_inner, dim3(1024), dim3(256), 0, stream,
                       children + 65472, contents + (size_t)65472 * NF,
                       w_u, b_u, wb, b_h, embB, embA);
    hipLaunchKernelGGL(k_tailA, dim3(1024), dim3(256), 0, stream,
                       ids_A, u_small, wb, b_h, embA, embB);
    hipLaunchKernelGGL(k_tailB, dim3(64), dim3(256), 0, stream,
                       ids_B, u_small, wb, b_h, embB, outf);
}